// Round 3
// baseline (1674.950 us; speedup 1.0000x reference)
//
#include <hip/hip_runtime.h>
#include <hip/hip_bf16.h>
#include <math.h>

// Problem constants (fixed by the reference)
#define LTOT 4096   // H*W = 64*64
#define DCH  96     // d_inner
#define NST  16     // d_state
#define RNK  6      // dt_rank
#define CPR  38     // R + 2N
#define KDIR 4

// Direction index maps. All four are involutions (H==W==64), which also makes
// them the path_overlay inverse maps: contribution of scan-step l of direction k
// lands at merged position idx_k(l).
__device__ __forceinline__ int dir_idx(int k, int l) {
  int a = l >> 6, c = l & 63;          // l = a*64 + c  (h=a, w=c for k=0)
  if (k == 0) return l;                // HW order
  if (k == 1) return (c << 6) + a;     // WH (transpose) order
  if (k == 2) return 4095 - l;         // reversed HW
  return ((63 - c) << 6) + (63 - a);   // reversed WH
}

// ---------------------------------------------------------------------------
// Kernel 1: projections.  thread = one l for one (s,b,k).
// x_dbl[c] = sum_d xs[d]*W[c,d]; delta = softplus(dt_w @ x_dbl[0:6] + dt_b);
// writes delta [s][b][k][d][l], B [s][b][k][n][l], C [s][b][k][n][l]
// ---------------------------------------------------------------------------
__global__ __launch_bounds__(256) void proj_kernel(
    const float* __restrict__ x, const float* __restrict__ y,
    const float* __restrict__ xw_d, const float* __restrict__ dtw_d, const float* __restrict__ dtb_d,
    const float* __restrict__ xw_c, const float* __restrict__ dtw_c, const float* __restrict__ dtb_c,
    float* __restrict__ deltaBuf, float* __restrict__ BBuf, float* __restrict__ CBuf)
{
  int l  = blockIdx.x * 256 + threadIdx.x;
  int k  = blockIdx.y;
  int sb = blockIdx.z;
  int s  = sb >> 2, b = sb & 3;

  const float* xin = s ? y     : x;
  const float* xw  = s ? xw_c  : xw_d;   // [K][38][96]
  const float* dtw = s ? dtw_c : dtw_d;  // [K][96][6]
  const float* dtb = s ? dtb_c : dtb_d;  // [K][96]

  int pos = dir_idx(k, l);
  const float* xb = xin + (size_t)b * DCH * LTOT;

  float acc[CPR];
  #pragma unroll
  for (int c = 0; c < CPR; ++c) acc[c] = 0.f;

  const float* Wk = xw + k * CPR * DCH;
  for (int d = 0; d < DCH; ++d) {
    float xv = xb[(size_t)d * LTOT + pos];
    #pragma unroll
    for (int c = 0; c < CPR; ++c) acc[c] = fmaf(xv, Wk[c * DCH + d], acc[c]);
  }

  const float* dwk = dtw + k * DCH * RNK;
  const float* dbk = dtb + k * DCH;
  float* dOut = deltaBuf + ((size_t)((s * 4 + b) * KDIR + k) * DCH) * LTOT + l;
  for (int d = 0; d < DCH; ++d) {
    float t = dbk[d];
    #pragma unroll
    for (int r = 0; r < RNK; ++r) t = fmaf(acc[r], dwk[d * RNK + r], t);
    // softplus
    float sp = (t > 20.f) ? t : log1pf(__expf(t));
    dOut[(size_t)d * LTOT] = sp;
  }

  float* Bo = BBuf + ((size_t)((s * 4 + b) * KDIR + k) * NST) * LTOT + l;
  float* Co = CBuf + ((size_t)((s * 4 + b) * KDIR + k) * NST) * LTOT + l;
  #pragma unroll
  for (int n = 0; n < NST; ++n) {
    Bo[(size_t)n * LTOT] = acc[RNK + n];
    Co[(size_t)n * LTOT] = acc[RNK + NST + n];
  }
}

// ---------------------------------------------------------------------------
// Kernel 2: selective scan + in-kernel path overlay.
// one wave (64 threads) per (s,b,d); lane = (k<<4)|n.
// Each lane integrates one state h over L; y contribution reduced over the
// 16-lane n-group, accumulated into LDS yy[pos] (merged over all 4 dirs).
// Cross-attention of C: stream s reads CBuf of stream 1-s.
// ---------------------------------------------------------------------------
__global__ __launch_bounds__(64) void scan_kernel(
    const float* __restrict__ x, const float* __restrict__ y,
    const float* __restrict__ Alog_d, const float* __restrict__ Ds_d,
    const float* __restrict__ Alog_c, const float* __restrict__ Ds_c,
    const float* __restrict__ deltaBuf, const float* __restrict__ BBuf,
    const float* __restrict__ CBuf, float* __restrict__ yyBuf)
{
  __shared__ float yy[LTOT];
  int lane = threadIdx.x;
  int k = lane >> 4, n = lane & 15;
  int d = blockIdx.x, b = blockIdx.y, s = blockIdx.z;

  const float* xin  = s ? y      : x;
  const float* Alog = s ? Alog_c : Alog_d;
  const float* Dsp  = s ? Ds_c   : Ds_d;

  float A  = -__expf(Alog[(k * DCH + d) * NST + n]);
  float Dv = Dsp[k * DCH + d];

  for (int i = lane; i < LTOT; i += 64) yy[i] = 0.f;
  __syncthreads();

  const float* dbase = deltaBuf + ((size_t)(((s * 4 + b) * KDIR + k) * DCH + d)) * LTOT;
  const float* Bbase = BBuf + ((size_t)(((s * 4 + b) * KDIR + k) * NST + n)) * LTOT;
  const float* Cbase = CBuf + ((size_t)((((1 - s) * 4 + b) * KDIR + k) * NST + n)) * LTOT; // crossed
  const float* xb    = xin + (size_t)(b * DCH + d) * LTOT;

  float h = 0.f;
  for (int l0 = 0; l0 < LTOT; l0 += 4) {
    float4 dv4 = *(const float4*)(dbase + l0);
    float4 bv4 = *(const float4*)(Bbase + l0);
    float4 cv4 = *(const float4*)(Cbase + l0);
    #pragma unroll
    for (int j = 0; j < 4; ++j) {
      int l = l0 + j;
      float delta = (&dv4.x)[j];
      int pos = dir_idx(k, l);
      float u = xb[pos];
      float dA = __expf(delta * A);
      h = fmaf(h, dA, delta * u * ((&bv4.x)[j]));
      float p = h * ((&cv4.x)[j]);
      // reduce over the 16 n-lanes of this k-group
      p += __shfl_xor(p, 8, 16);
      p += __shfl_xor(p, 4, 16);
      p += __shfl_xor(p, 2, 16);
      p += __shfl_xor(p, 1, 16);
      if (n == 0) {
        // 4 k-lanes may collide on diagonals -> LDS atomic
        atomicAdd(&yy[pos], p + u * Dv);
      }
    }
  }
  __syncthreads();

  float* out = yyBuf + (size_t)((s * 4 + b) * DCH + d) * LTOT;
  for (int i = lane; i < LTOT; i += 64) out[i] = yy[i];
}

// ---------------------------------------------------------------------------
// Kernel 3: layernorm over channels + final transpose to [B,D,H,W].
// thread = one spatial position p for one (s,b).
// ---------------------------------------------------------------------------
__global__ __launch_bounds__(256) void merge_ln_kernel(
    const float* __restrict__ yyBuf,
    const float* __restrict__ ln1s, const float* __restrict__ ln1b,
    const float* __restrict__ ln2s, const float* __restrict__ ln2b,
    float* __restrict__ out)
{
  int p = blockIdx.x * 256 + threadIdx.x;
  int b = blockIdx.y, s = blockIdx.z;

  const float* base = yyBuf + ((size_t)(s * 4 + b) * DCH) * LTOT + p;
  float v[DCH];
  float m = 0.f;
  #pragma unroll
  for (int d = 0; d < DCH; ++d) { v[d] = base[(size_t)d * LTOT]; m += v[d]; }
  m *= (1.f / DCH);
  float var = 0.f;
  #pragma unroll
  for (int d = 0; d < DCH; ++d) { float t = v[d] - m; var = fmaf(t, t, var); }
  var *= (1.f / DCH);
  float r = rsqrtf(var + 1e-5f);

  const float* sc = s ? ln2s : ln1s;
  const float* bi = s ? ln2b : ln1b;
  float* ob = out + ((size_t)(s * 4 + b) * DCH) * LTOT + p;
  #pragma unroll
  for (int d = 0; d < DCH; ++d) ob[(size_t)d * LTOT] = (v[d] - m) * r * sc[d] + bi[d];
}

// ---------------------------------------------------------------------------
extern "C" void kernel_launch(void* const* d_in, const int* in_sizes, int n_in,
                              void* d_out, int out_size, void* d_ws, size_t ws_size,
                              hipStream_t stream)
{
  const float* x      = (const float*)d_in[0];
  const float* y      = (const float*)d_in[1];
  const float* xw_d   = (const float*)d_in[2];
  const float* dtw_d  = (const float*)d_in[3];
  const float* dtb_d  = (const float*)d_in[4];
  const float* Alog_d = (const float*)d_in[5];
  const float* Ds_d   = (const float*)d_in[6];
  const float* xw_c   = (const float*)d_in[7];
  const float* dtw_c  = (const float*)d_in[8];
  const float* dtb_c  = (const float*)d_in[9];
  const float* Alog_c = (const float*)d_in[10];
  const float* Ds_c   = (const float*)d_in[11];
  const float* ln1s   = (const float*)d_in[12];
  const float* ln1b   = (const float*)d_in[13];
  const float* ln2s   = (const float*)d_in[14];
  const float* ln2b   = (const float*)d_in[15];

  float* ws = (float*)d_ws;
  // workspace layout (floats):
  //   deltaBuf: 2*4*4*96*4096 = 6,291,456
  //   BBuf:     2*4*4*16*4096 = 2,097,152
  //   CBuf:     2*4*4*16*4096 = 2,097,152
  //   yyBuf:    2*4*96*4096   = 3,145,728     total ~54.5 MB
  float* deltaBuf = ws;
  float* BBuf  = deltaBuf + (size_t)2 * 4 * KDIR * DCH * LTOT;
  float* CBuf  = BBuf + (size_t)2 * 4 * KDIR * NST * LTOT;
  float* yyBuf = CBuf + (size_t)2 * 4 * KDIR * NST * LTOT;
  float* outF  = (float*)d_out;

  dim3 pg(LTOT / 256, KDIR, 8);   // (l-chunks, k, s*4+b)
  hipLaunchKernelGGL(proj_kernel, pg, dim3(256), 0, stream,
                     x, y, xw_d, dtw_d, dtb_d, xw_c, dtw_c, dtb_c,
                     deltaBuf, BBuf, CBuf);

  dim3 sg(DCH, 4, 2);             // (d, b, s), one wave each
  hipLaunchKernelGGL(scan_kernel, sg, dim3(64), 0, stream,
                     x, y, Alog_d, Ds_d, Alog_c, Ds_c,
                     deltaBuf, BBuf, CBuf, yyBuf);

  dim3 mg(LTOT / 256, 4, 2);      // (p-chunks, b, s)
  hipLaunchKernelGGL(merge_ln_kernel, mg, dim3(256), 0, stream,
                     yyBuf, ln1s, ln1b, ln2s, ln2b, outF);
}

// Round 5
// 500.000 us; speedup vs baseline: 3.3499x; 3.3499x over previous
//
#include <hip/hip_runtime.h>
#include <hip/hip_bf16.h>
#include <math.h>

// Problem constants (fixed by the reference)
#define LTOT 4096   // H*W = 64*64
#define DCH  96     // d_inner
#define NST  16     // d_state
#define RNK  6      // dt_rank
#define CPR  38     // R + 2N
#define KDIR 4
#define NCH  16     // scan chunks per (s,b,d)  (= waves per block)
#define CHUNK (LTOT / NCH)   // 256 steps per chunk

// Direction index maps. All four are involutions (H==W==64), which also makes
// them the path_overlay inverse maps: contribution of scan-step l of direction k
// lands at merged position idx_k(l).
__device__ __forceinline__ int dir_idx(int k, int l) {
  int a = l >> 6, c = l & 63;          // l = a*64 + c  (h=a, w=c for k=0)
  if (k == 0) return l;                // HW order
  if (k == 1) return (c << 6) + a;     // WH (transpose) order
  if (k == 2) return 4095 - l;         // reversed HW
  return ((63 - c) << 6) + (63 - a);   // reversed WH
}

// ---------------------------------------------------------------------------
// Kernel 1: projections.  thread = one l for one (s,b,k).
// x_dbl[c] = sum_d xs[d]*W[c,d]; delta = softplus(dt_w @ x_dbl[0:6] + dt_b);
// writes delta [s][b][k][d][l], B/C interleaved [s][b][k][l][n]  (n fastest,
// so the scan's 16 n-lanes read 64 contiguous bytes per step).
// ---------------------------------------------------------------------------
__global__ __launch_bounds__(256) void proj_kernel(
    const float* __restrict__ x, const float* __restrict__ y,
    const float* __restrict__ xw_d, const float* __restrict__ dtw_d, const float* __restrict__ dtb_d,
    const float* __restrict__ xw_c, const float* __restrict__ dtw_c, const float* __restrict__ dtb_c,
    float* __restrict__ deltaBuf, float* __restrict__ BBuf, float* __restrict__ CBuf)
{
  int l  = blockIdx.x * 256 + threadIdx.x;
  int k  = blockIdx.y;
  int sb = blockIdx.z;
  int s  = sb >> 2, b = sb & 3;

  const float* xin = s ? y     : x;
  const float* xw  = s ? xw_c  : xw_d;   // [K][38][96]
  const float* dtw = s ? dtw_c : dtw_d;  // [K][96][6]
  const float* dtb = s ? dtb_c : dtb_d;  // [K][96]

  int pos = dir_idx(k, l);
  const float* xb = xin + (size_t)b * DCH * LTOT;

  float acc[CPR];
  #pragma unroll
  for (int c = 0; c < CPR; ++c) acc[c] = 0.f;

  const float* Wk = xw + k * CPR * DCH;
  for (int d = 0; d < DCH; ++d) {
    float xv = xb[(size_t)d * LTOT + pos];
    #pragma unroll
    for (int c = 0; c < CPR; ++c) acc[c] = fmaf(xv, Wk[c * DCH + d], acc[c]);
  }

  const float* dwk = dtw + k * DCH * RNK;
  const float* dbk = dtb + k * DCH;
  float* dOut = deltaBuf + ((size_t)((s * 4 + b) * KDIR + k) * DCH) * LTOT + l;
  for (int d = 0; d < DCH; ++d) {
    float t = dbk[d];
    #pragma unroll
    for (int r = 0; r < RNK; ++r) t = fmaf(acc[r], dwk[d * RNK + r], t);
    // softplus
    float sp = (t > 20.f) ? t : log1pf(__expf(t));
    dOut[(size_t)d * LTOT] = sp;
  }

  // interleaved [l][n] writes: 16 consecutive floats per thread = 4x float4,
  // consecutive threads write consecutive 64B chunks (fully coalesced)
  float* Bo = BBuf + ((size_t)((s * 4 + b) * KDIR + k) * LTOT + l) * NST;
  float* Co = CBuf + ((size_t)((s * 4 + b) * KDIR + k) * LTOT + l) * NST;
  #pragma unroll
  for (int q = 0; q < 4; ++q) {
    float4 bv = make_float4(acc[RNK + 4*q], acc[RNK + 4*q+1], acc[RNK + 4*q+2], acc[RNK + 4*q+3]);
    float4 cv = make_float4(acc[RNK+NST + 4*q], acc[RNK+NST + 4*q+1], acc[RNK+NST + 4*q+2], acc[RNK+NST + 4*q+3]);
    ((float4*)Bo)[q] = bv;
    ((float4*)Co)[q] = cv;
  }
}

// ---------------------------------------------------------------------------
// Kernel 2: chunked selective scan + in-kernel path overlay, fused per (s,b,d).
// Block = 1024 threads = 16 waves; wave c owns chunk c (256 steps).
// Lane = (k<<4)|n within each wave.
// Phase 1: chunk-local scan (h0=0), record h_loc and chunk decay P=exp(A*sum_delta).
// Phase 2: 16-step carry scan across chunks (wave 0, via LDS).
// Phase 3: re-scan chunk from true h_in, reduce y over n-lanes, accumulate
//          merged overlay into LDS yy[pos] (LDS atomics across k and chunks).
// Cross-stream C: stream s reads CBuf of stream 1-s.
// ---------------------------------------------------------------------------
__global__ __launch_bounds__(1024) void scan_kernel(
    const float* __restrict__ x, const float* __restrict__ y,
    const float* __restrict__ Alog_d, const float* __restrict__ Ds_d,
    const float* __restrict__ Alog_c, const float* __restrict__ Ds_c,
    const float* __restrict__ deltaBuf, const float* __restrict__ BBuf,
    const float* __restrict__ CBuf, float* __restrict__ yyBuf)
{
  __shared__ float yy[LTOT];        // 16 KB merged overlay accumulator
  __shared__ float xrow[LTOT];      // 16 KB staged x row (all dirs read it)
  __shared__ float hloc[NCH][64];   // 4 KB chunk-local final states
  __shared__ float Pc[NCH][64];     // 4 KB chunk decay products
  __shared__ float hin[NCH][64];    // 4 KB chunk carry-in states

  int tid  = threadIdx.x;
  int c    = tid >> 6;              // chunk id = wave id
  int lane = tid & 63;
  int k = lane >> 4, n = lane & 15;
  int d = blockIdx.x, b = blockIdx.y, s = blockIdx.z;

  const float* xin  = s ? y      : x;
  const float* Alog = s ? Alog_c : Alog_d;
  const float* Dsp  = s ? Ds_c   : Ds_d;

  float A  = -__expf(Alog[(k * DCH + d) * NST + n]);
  float Dv = Dsp[k * DCH + d];

  // cooperative init: zero yy, stage x row (coalesced float4)
  const float* xb = xin + (size_t)(b * DCH + d) * LTOT;
  {
    float4 xv = ((const float4*)xb)[tid];         // 1024 * 4 floats = 4096
    ((float4*)xrow)[tid] = xv;
    ((float4*)yy)[tid] = make_float4(0.f, 0.f, 0.f, 0.f);
  }
  __syncthreads();

  const float* dbase = deltaBuf + ((size_t)(((s * 4 + b) * KDIR + k) * DCH + d)) * LTOT;
  const float* Bbase = BBuf + ((size_t)((s * 4 + b) * KDIR + k)) * LTOT * NST;
  const float* Cbase = CBuf + ((size_t)(((1 - s) * 4 + b) * KDIR + k)) * LTOT * NST; // crossed
  const int l0beg = c * CHUNK;

  // ---- phase 1: local scan, no y ----
  float h = 0.f, sumd = 0.f;
  for (int l0 = l0beg; l0 < l0beg + CHUNK; l0 += 4) {
    float4 dv4 = *(const float4*)(dbase + l0);
    #pragma unroll
    for (int j = 0; j < 4; ++j) {
      int l = l0 + j;
      float delta = (&dv4.x)[j];
      float Bv = Bbase[(size_t)l * NST + n];
      float u  = xrow[dir_idx(k, l)];
      sumd += delta;
      h = fmaf(h, __expf(delta * A), delta * u * Bv);
    }
  }
  hloc[c][lane] = h;
  Pc[c][lane]   = __expf(A * sumd);
  __syncthreads();

  // ---- phase 2: carry scan over chunks (wave 0 only; exact: linear recurrence) ----
  if (tid < 64) {
    float hh = 0.f;
    hin[0][lane] = 0.f;
    for (int cc = 1; cc < NCH; ++cc) {
      hh = fmaf(Pc[cc - 1][lane], hh, hloc[cc - 1][lane]);
      hin[cc][lane] = hh;
    }
  }
  __syncthreads();

  // ---- phase 3: full scan from true carry-in, y + overlay ----
  h = hin[c][lane];
  for (int l0 = l0beg; l0 < l0beg + CHUNK; l0 += 4) {
    float4 dv4 = *(const float4*)(dbase + l0);
    #pragma unroll
    for (int j = 0; j < 4; ++j) {
      int l = l0 + j;
      float delta = (&dv4.x)[j];
      float Bv = Bbase[(size_t)l * NST + n];
      float Cv = Cbase[(size_t)l * NST + n];
      int pos  = dir_idx(k, l);
      float u  = xrow[pos];
      h = fmaf(h, __expf(delta * A), delta * u * Bv);
      float p = h * Cv;
      // reduce over the 16 n-lanes of this k-group
      p += __shfl_xor(p, 8, 16);
      p += __shfl_xor(p, 4, 16);
      p += __shfl_xor(p, 2, 16);
      p += __shfl_xor(p, 1, 16);
      if (n == 0) {
        atomicAdd(&yy[pos], p + u * Dv);   // merge across 4 k-lanes + 16 chunks
      }
    }
  }
  __syncthreads();

  float* out = yyBuf + (size_t)((s * 4 + b) * DCH + d) * LTOT;
  {
    float4 v = ((const float4*)yy)[tid];
    ((float4*)out)[tid] = v;
  }
}

// ---------------------------------------------------------------------------
// Kernel 3: layernorm over channels + final transpose to [B,D,H,W].
// thread = one spatial position p for one (s,b).
// ---------------------------------------------------------------------------
__global__ __launch_bounds__(256) void merge_ln_kernel(
    const float* __restrict__ yyBuf,
    const float* __restrict__ ln1s, const float* __restrict__ ln1b,
    const float* __restrict__ ln2s, const float* __restrict__ ln2b,
    float* __restrict__ out)
{
  int p = blockIdx.x * 256 + threadIdx.x;
  int b = blockIdx.y, s = blockIdx.z;

  const float* base = yyBuf + ((size_t)(s * 4 + b) * DCH) * LTOT + p;
  float v[DCH];
  float m = 0.f;
  #pragma unroll
  for (int d = 0; d < DCH; ++d) { v[d] = base[(size_t)d * LTOT]; m += v[d]; }
  m *= (1.f / DCH);
  float var = 0.f;
  #pragma unroll
  for (int d = 0; d < DCH; ++d) { float t = v[d] - m; var = fmaf(t, t, var); }
  var *= (1.f / DCH);
  float r = rsqrtf(var + 1e-5f);

  const float* sc = s ? ln2s : ln1s;
  const float* bi = s ? ln2b : ln1b;
  float* ob = out + ((size_t)(s * 4 + b) * DCH) * LTOT + p;
  #pragma unroll
  for (int d = 0; d < DCH; ++d) ob[(size_t)d * LTOT] = (v[d] - m) * r * sc[d] + bi[d];
}

// ---------------------------------------------------------------------------
extern "C" void kernel_launch(void* const* d_in, const int* in_sizes, int n_in,
                              void* d_out, int out_size, void* d_ws, size_t ws_size,
                              hipStream_t stream)
{
  const float* x      = (const float*)d_in[0];
  const float* y      = (const float*)d_in[1];
  const float* xw_d   = (const float*)d_in[2];
  const float* dtw_d  = (const float*)d_in[3];
  const float* dtb_d  = (const float*)d_in[4];
  const float* Alog_d = (const float*)d_in[5];
  const float* Ds_d   = (const float*)d_in[6];
  const float* xw_c   = (const float*)d_in[7];
  const float* dtw_c  = (const float*)d_in[8];
  const float* dtb_c  = (const float*)d_in[9];
  const float* Alog_c = (const float*)d_in[10];
  const float* Ds_c   = (const float*)d_in[11];
  const float* ln1s   = (const float*)d_in[12];
  const float* ln1b   = (const float*)d_in[13];
  const float* ln2s   = (const float*)d_in[14];
  const float* ln2b   = (const float*)d_in[15];

  float* ws = (float*)d_ws;
  // workspace layout (floats):
  //   deltaBuf: 2*4*4*96*4096 = 6,291,456
  //   BBuf:     2*4*4*4096*16 = 2,097,152   (interleaved [l][n])
  //   CBuf:     2*4*4*4096*16 = 2,097,152   (interleaved [l][n])
  //   yyBuf:    2*4*96*4096   = 3,145,728     total ~54.5 MB
  float* deltaBuf = ws;
  float* BBuf  = deltaBuf + (size_t)2 * 4 * KDIR * DCH * LTOT;
  float* CBuf  = BBuf + (size_t)2 * 4 * KDIR * NST * LTOT;
  float* yyBuf = CBuf + (size_t)2 * 4 * KDIR * NST * LTOT;
  float* outF  = (float*)d_out;

  dim3 pg(LTOT / 256, KDIR, 8);   // (l-chunks, k, s*4+b)
  hipLaunchKernelGGL(proj_kernel, pg, dim3(256), 0, stream,
                     x, y, xw_d, dtw_d, dtb_d, xw_c, dtw_c, dtb_c,
                     deltaBuf, BBuf, CBuf);

  dim3 sg(DCH, 4, 2);             // (d, b, s): one 16-wave block each
  hipLaunchKernelGGL(scan_kernel, sg, dim3(1024), 0, stream,
                     x, y, Alog_d, Ds_d, Alog_c, Ds_c,
                     deltaBuf, BBuf, CBuf, yyBuf);

  dim3 mg(LTOT / 256, 4, 2);      // (p-chunks, b, s)
  hipLaunchKernelGGL(merge_ln_kernel, mg, dim3(256), 0, stream,
                     yyBuf, ln1s, ln1b, ln2s, ln2b, outF);
}

// Round 8
// 401.424 us; speedup vs baseline: 4.1725x; 1.2456x over previous
//
#include <hip/hip_runtime.h>
#include <hip/hip_bf16.h>
#include <math.h>

// Problem constants (fixed by the reference)
#define LTOT 4096   // H*W = 64*64
#define DCH  96     // d_inner
#define NST  16     // d_state
#define RNK  6      // dt_rank
#define CPR  38     // R + 2N
#define KDIR 4
#define NCH  16     // scan chunks per (s,b,d)  (= waves per block)
#define CHUNK (LTOT / NCH)   // 256 steps per chunk

// Direction index maps. All four are involutions (H==W==64), which also makes
// them the path_overlay inverse maps: contribution of scan-step l of direction k
// lands at merged position idx_k(l).
__device__ __forceinline__ int dir_idx(int k, int l) {
  int a = l >> 6, c = l & 63;          // l = a*64 + c  (h=a, w=c for k=0)
  if (k == 0) return l;                // HW order
  if (k == 1) return (c << 6) + a;     // WH (transpose) order
  if (k == 2) return 4095 - l;         // reversed HW
  return ((63 - c) << 6) + (63 - a);   // reversed WH
}

// DPP row_shl fused add: lane i += lane i+N within its 16-lane DPP row
// (row_shl:N ctrl = 0x100|N; data moves toward lower lanes, out-of-row -> 0
// via bound_ctrl). After stages 8,4,2,1 lane n==0 of each row holds the sum.
// CTRL must be a compile-time constant -> template parameter.
template <int CTRL>
__device__ __forceinline__ float row_shl_add(float p) {
  int moved = __builtin_amdgcn_update_dpp(0, __float_as_int(p), CTRL, 0xF, 0xF, true);
  return p + __int_as_float(moved);
}

// ---------------------------------------------------------------------------
// Kernel 1: projections.  thread = one l for one (s,b,k).
// ---------------------------------------------------------------------------
__global__ __launch_bounds__(256) void proj_kernel(
    const float* __restrict__ x, const float* __restrict__ y,
    const float* __restrict__ xw_d, const float* __restrict__ dtw_d, const float* __restrict__ dtb_d,
    const float* __restrict__ xw_c, const float* __restrict__ dtw_c, const float* __restrict__ dtb_c,
    float* __restrict__ deltaBuf, float* __restrict__ BBuf, float* __restrict__ CBuf)
{
  int l  = blockIdx.x * 256 + threadIdx.x;
  int k  = blockIdx.y;
  int sb = blockIdx.z;
  int s  = sb >> 2, b = sb & 3;

  const float* xin = s ? y     : x;
  const float* xw  = s ? xw_c  : xw_d;   // [K][38][96]
  const float* dtw = s ? dtw_c : dtw_d;  // [K][96][6]
  const float* dtb = s ? dtb_c : dtb_d;  // [K][96]

  int pos = dir_idx(k, l);
  const float* xb = xin + (size_t)b * DCH * LTOT;

  float acc[CPR];
  #pragma unroll
  for (int c = 0; c < CPR; ++c) acc[c] = 0.f;

  const float* Wk = xw + k * CPR * DCH;
  for (int d = 0; d < DCH; ++d) {
    float xv = xb[(size_t)d * LTOT + pos];
    #pragma unroll
    for (int c = 0; c < CPR; ++c) acc[c] = fmaf(xv, Wk[c * DCH + d], acc[c]);
  }

  const float* dwk = dtw + k * DCH * RNK;
  const float* dbk = dtb + k * DCH;
  float* dOut = deltaBuf + ((size_t)((s * 4 + b) * KDIR + k) * DCH) * LTOT + l;
  for (int d = 0; d < DCH; ++d) {
    float t = dbk[d];
    #pragma unroll
    for (int r = 0; r < RNK; ++r) t = fmaf(acc[r], dwk[d * RNK + r], t);
    // softplus
    float sp = (t > 20.f) ? t : log1pf(__expf(t));
    dOut[(size_t)d * LTOT] = sp;
  }

  // interleaved [l][n] writes: fully coalesced float4s
  float* Bo = BBuf + ((size_t)((s * 4 + b) * KDIR + k) * LTOT + l) * NST;
  float* Co = CBuf + ((size_t)((s * 4 + b) * KDIR + k) * LTOT + l) * NST;
  #pragma unroll
  for (int q = 0; q < 4; ++q) {
    float4 bv = make_float4(acc[RNK + 4*q], acc[RNK + 4*q+1], acc[RNK + 4*q+2], acc[RNK + 4*q+3]);
    float4 cv = make_float4(acc[RNK+NST + 4*q], acc[RNK+NST + 4*q+1], acc[RNK+NST + 4*q+2], acc[RNK+NST + 4*q+3]);
    ((float4*)Bo)[q] = bv;
    ((float4*)Co)[q] = cv;
  }
}

// ---------------------------------------------------------------------------
// Kernel 2: chunked selective scan + in-kernel path overlay, fused per (s,b,d).
// Block = 1024 threads = 16 waves; wave c owns chunk c (256 steps).
// Lane = (k<<4)|n.  Per-step cost minimized: incremental pos (2 VALU),
// exp2 with prefolded log2e, DPP-row reduce (4 VALU), D-term hoisted out.
// ---------------------------------------------------------------------------
__global__ __launch_bounds__(1024) void scan_kernel(
    const float* __restrict__ x, const float* __restrict__ y,
    const float* __restrict__ Alog_d, const float* __restrict__ Ds_d,
    const float* __restrict__ Alog_c, const float* __restrict__ Ds_c,
    const float* __restrict__ deltaBuf, const float* __restrict__ BBuf,
    const float* __restrict__ CBuf, float* __restrict__ yyBuf)
{
  __shared__ float yy[LTOT];        // 16 KB merged overlay accumulator
  __shared__ float xrow[LTOT];      // 16 KB staged x row
  __shared__ float hloc[NCH][64];
  __shared__ float Pc[NCH][64];
  __shared__ float hin[NCH][64];

  int tid  = threadIdx.x;
  int c    = tid >> 6;              // chunk id = wave id
  int lane = tid & 63;
  int k = lane >> 4, n = lane & 15;
  int d = blockIdx.x, b = blockIdx.y, s = blockIdx.z;

  const float* xin  = s ? y      : x;
  const float* Alog = s ? Alog_c : Alog_d;
  const float* Dsp  = s ? Ds_c   : Ds_d;

  float A2 = -__expf(Alog[(k * DCH + d) * NST + n]) * 1.44269504088896341f; // A*log2(e)

  // cooperative init: zero yy, stage x row (coalesced float4)
  const float* xb = xin + (size_t)(b * DCH + d) * LTOT;
  {
    float4 xv = ((const float4*)xb)[tid];
    ((float4*)xrow)[tid] = xv;
    ((float4*)yy)[tid] = make_float4(0.f, 0.f, 0.f, 0.f);
  }
  __syncthreads();

  const float* dbase = deltaBuf + ((size_t)(((s * 4 + b) * KDIR + k) * DCH + d)) * LTOT;
  const float* Bbase = BBuf + ((size_t)((s * 4 + b) * KDIR + k)) * LTOT * NST;
  const float* Cbase = CBuf + ((size_t)(((1 - s) * 4 + b) * KDIR + k)) * LTOT * NST; // crossed
  const int l0beg = c * CHUNK;

  // incremental pos (byte offsets): per-k step deltas + wrap deltas at (l&63)==63
  const int dpn  = (k & 2 ? -1 : 1) * (k & 1 ? 64 : 1);
  const int dpw  = (k & 1) ? ((k & 2) ? 4031 : -4031) : dpn;
  const int dpnB = dpn * 4, dpwB = dpw * 4;

  // ---- phase 1: local scan (h0=0), accumulate sum of delta ----
  float h = 0.f, sumd = 0.f;
  {
    int posB = dir_idx(k, l0beg) * 4;
    const float* Bp = Bbase + (size_t)l0beg * NST + n;
    for (int l0 = l0beg; l0 < l0beg + CHUNK; l0 += 4) {
      float4 dv4 = *(const float4*)(dbase + l0);
      #pragma unroll
      for (int j = 0; j < 4; ++j) {
        float delta = (&dv4.x)[j];
        float Bv = Bp[j * NST];
        float u  = *(const float*)((const char*)xrow + posB);
        sumd += delta;
        h = fmaf(h, exp2f(delta * A2), delta * u * Bv);
        posB += (((l0 + j) & 63) == 63) ? dpwB : dpnB;
      }
      Bp += 4 * NST;
    }
  }
  hloc[c][lane] = h;
  Pc[c][lane]   = exp2f(A2 * sumd);
  __syncthreads();

  // ---- phase 2: carry scan over chunks (wave 0; exact, linear recurrence) ----
  if (tid < 64) {
    float hh = 0.f;
    hin[0][lane] = 0.f;
    for (int cc = 1; cc < NCH; ++cc) {
      hh = fmaf(Pc[cc - 1][lane], hh, hloc[cc - 1][lane]);
      hin[cc][lane] = hh;
    }
  }
  __syncthreads();

  // ---- phase 3: full scan from true carry-in, y + overlay ----
  h = hin[c][lane];
  {
    int posB = dir_idx(k, l0beg) * 4;
    const float* Bp = Bbase + (size_t)l0beg * NST + n;
    const float* Cp = Cbase + (size_t)l0beg * NST + n;
    for (int l0 = l0beg; l0 < l0beg + CHUNK; l0 += 4) {
      float4 dv4 = *(const float4*)(dbase + l0);
      #pragma unroll
      for (int j = 0; j < 4; ++j) {
        float delta = (&dv4.x)[j];
        float Bv = Bp[j * NST];
        float Cv = Cp[j * NST];
        float u  = *(const float*)((const char*)xrow + posB);
        h = fmaf(h, exp2f(delta * A2), delta * u * Bv);
        float p = h * Cv;
        // DPP row-reduce over the 16 n-lanes: sum lands in n==0 (row_shl)
        p = row_shl_add<0x108>(p);  // row_shl:8
        p = row_shl_add<0x104>(p);  // row_shl:4
        p = row_shl_add<0x102>(p);  // row_shl:2
        p = row_shl_add<0x101>(p);  // row_shl:1
        if (n == 0) {
          atomicAdd((float*)((char*)yy + posB), p);  // merge across k + chunks
        }
        posB += (((l0 + j) & 63) == 63) ? dpwB : dpnB;
      }
      Bp += 4 * NST;
      Cp += 4 * NST;
    }
  }
  __syncthreads();

  // writeback with hoisted D-skip term: sum_k u*Dv_k = xrow[m] * Dsum
  float Dsum = Dsp[0 * DCH + d] + Dsp[1 * DCH + d] + Dsp[2 * DCH + d] + Dsp[3 * DCH + d];
  float* out = yyBuf + (size_t)((s * 4 + b) * DCH + d) * LTOT;
  {
    float4 v  = ((const float4*)yy)[tid];
    float4 xv = ((const float4*)xrow)[tid];
    v.x = fmaf(xv.x, Dsum, v.x);
    v.y = fmaf(xv.y, Dsum, v.y);
    v.z = fmaf(xv.z, Dsum, v.z);
    v.w = fmaf(xv.w, Dsum, v.w);
    ((float4*)out)[tid] = v;
  }
}

// ---------------------------------------------------------------------------
// Kernel 3: layernorm over channels + final transpose to [B,D,H,W].
// ---------------------------------------------------------------------------
__global__ __launch_bounds__(256) void merge_ln_kernel(
    const float* __restrict__ yyBuf,
    const float* __restrict__ ln1s, const float* __restrict__ ln1b,
    const float* __restrict__ ln2s, const float* __restrict__ ln2b,
    float* __restrict__ out)
{
  int p = blockIdx.x * 256 + threadIdx.x;
  int b = blockIdx.y, s = blockIdx.z;

  const float* base = yyBuf + ((size_t)(s * 4 + b) * DCH) * LTOT + p;
  float v[DCH];
  float m = 0.f;
  #pragma unroll
  for (int d = 0; d < DCH; ++d) { v[d] = base[(size_t)d * LTOT]; m += v[d]; }
  m *= (1.f / DCH);
  float var = 0.f;
  #pragma unroll
  for (int d = 0; d < DCH; ++d) { float t = v[d] - m; var = fmaf(t, t, var); }
  var *= (1.f / DCH);
  float r = rsqrtf(var + 1e-5f);

  const float* sc = s ? ln2s : ln1s;
  const float* bi = s ? ln2b : ln1b;
  float* ob = out + ((size_t)(s * 4 + b) * DCH) * LTOT + p;
  #pragma unroll
  for (int d = 0; d < DCH; ++d) ob[(size_t)d * LTOT] = (v[d] - m) * r * sc[d] + bi[d];
}

// ---------------------------------------------------------------------------
extern "C" void kernel_launch(void* const* d_in, const int* in_sizes, int n_in,
                              void* d_out, int out_size, void* d_ws, size_t ws_size,
                              hipStream_t stream)
{
  const float* x      = (const float*)d_in[0];
  const float* y      = (const float*)d_in[1];
  const float* xw_d   = (const float*)d_in[2];
  const float* dtw_d  = (const float*)d_in[3];
  const float* dtb_d  = (const float*)d_in[4];
  const float* Alog_d = (const float*)d_in[5];
  const float* Ds_d   = (const float*)d_in[6];
  const float* xw_c   = (const float*)d_in[7];
  const float* dtw_c  = (const float*)d_in[8];
  const float* dtb_c  = (const float*)d_in[9];
  const float* Alog_c = (const float*)d_in[10];
  const float* Ds_c   = (const float*)d_in[11];
  const float* ln1s   = (const float*)d_in[12];
  const float* ln1b   = (const float*)d_in[13];
  const float* ln2s   = (const float*)d_in[14];
  const float* ln2b   = (const float*)d_in[15];

  float* ws = (float*)d_ws;
  float* deltaBuf = ws;
  float* BBuf  = deltaBuf + (size_t)2 * 4 * KDIR * DCH * LTOT;
  float* CBuf  = BBuf + (size_t)2 * 4 * KDIR * NST * LTOT;
  float* yyBuf = CBuf + (size_t)2 * 4 * KDIR * NST * LTOT;
  float* outF  = (float*)d_out;

  dim3 pg(LTOT / 256, KDIR, 8);   // (l-chunks, k, s*4+b)
  hipLaunchKernelGGL(proj_kernel, pg, dim3(256), 0, stream,
                     x, y, xw_d, dtw_d, dtb_d, xw_c, dtw_c, dtb_c,
                     deltaBuf, BBuf, CBuf);

  dim3 sg(DCH, 4, 2);             // (d, b, s): one 16-wave block each
  hipLaunchKernelGGL(scan_kernel, sg, dim3(1024), 0, stream,
                     x, y, Alog_d, Ds_d, Alog_c, Ds_c,
                     deltaBuf, BBuf, CBuf, yyBuf);

  dim3 mg(LTOT / 256, 4, 2);      // (p-chunks, b, s)
  hipLaunchKernelGGL(merge_ln_kernel, mg, dim3(256), 0, stream,
                     yyBuf, ln1s, ln1b, ln2s, ln2b, outF);
}